// Round 5
// baseline (545.304 us; speedup 1.0000x reference)
//
#include <hip/hip_runtime.h>
#include <climits>
#include <math.h>

#define PAD_IDX 1
#define SEP_ID 4

// clang-native 16B vector
typedef float floatx4 __attribute__((ext_vector_type(4)));

// Fully fused, read-free embedding. Grid = rows*64 blocks, 256 threads.
// Each block owns 64 consecutive output rows (one 64-token segment of one
// batch row).
//   A) whole block scans the full 4096-token row (redundant across the 64
//      blocks of a row, but L2-hot and parallel) -> running max sep idx /
//      min pad idx via Hillis-Steele in LDS.
//   B) the 4 owning threads emit this segment's 64 positions into LDS.
//   C) in-register sinusoid, with a PAD FAST PATH: positions after the
//      first padding token are all 1 -> zero output rows. With uniform
//      tokens in [0,1000) the first pad lands at ~index 983, so ~76% of
//      all rows are zeros. posBuf[r] is block-uniform, so the p==1 branch
//      is divergence-free and skips the 4-sinf chain (~112 VALU instrs)
//      that round-4 profiling arithmetic showed was throttling the write
//      stream (sinf VALU ~64% of issue ceiling at 6.3 TB/s store rate).
//      Non-pad rows keep the exact fp32 op chain of the reference
//      (expf / sinf / cosf on fl32 products), so absmax is unchanged.
__global__ __launch_bounds__(256) void fused_kernel(const int* __restrict__ tokens,
                                                    floatx4* __restrict__ out,
                                                    int seq_len) {
    const int b   = blockIdx.x >> 6;      // batch row
    const int seg = blockIdx.x & 63;      // 64-row segment within the row
    const int t   = threadIdx.x;
    const int rbase = b * seq_len;
    const int ebase = t * 16;

    // ---- Phase A: full-row scan ----
    int toks[16];
    const int4* tp = (const int4*)(tokens + rbase + ebase);
    #pragma unroll
    for (int k = 0; k < 4; ++k) {
        int4 v = tp[k];
        toks[k*4+0] = v.x; toks[k*4+1] = v.y; toks[k*4+2] = v.z; toks[k*4+3] = v.w;
    }

    int localMaxSep = 0;          // identity for running-max of sep_j (ref uses 0)
    int localMinPad = INT_MAX;    // identity for first-pad index
    #pragma unroll
    for (int k = 0; k < 16; ++k) {
        int j = ebase + k;
        if (toks[k] == SEP_ID)  localMaxSep = max(localMaxSep, j);
        if (toks[k] == PAD_IDX) localMinPad = min(localMinPad, j);
    }

    __shared__ int sMax[256];
    __shared__ int sMin[256];
    __shared__ int posBuf[64];
    sMax[t] = localMaxSep;
    sMin[t] = localMinPad;
    __syncthreads();
    for (int off = 1; off < 256; off <<= 1) {
        int vM = 0, vN = INT_MAX;
        if (t >= off) { vM = sMax[t - off]; vN = sMin[t - off]; }
        __syncthreads();
        sMax[t] = max(sMax[t], vM);
        sMin[t] = min(sMin[t], vN);
        __syncthreads();
    }

    // ---- Phase B: emit this segment's 64 positions ----
    int lastSep  = (t > 0) ? sMax[t - 1] : 0;
    int firstPad = (t > 0) ? sMin[t - 1] : INT_MAX;
    if ((t >> 2) == seg) {        // threads seg*4 .. seg*4+3 own tokens [seg*64, seg*64+64)
        #pragma unroll
        for (int k = 0; k < 16; ++k) {
            int j   = ebase + k;
            int tok = toks[k];
            if (tok == PAD_IDX) firstPad = min(firstPad, j);   // inclusive (cumprod)
            if (tok == SEP_ID)  lastSep  = max(lastSep, j);    // inclusive scan of sep_j
            posBuf[(t & 3) * 16 + k] = (firstPad <= j) ? 1 : (j - lastSep + 2);
        }
    }
    __syncthreads();

    // ---- Phase C: compute 64 output rows in-register ----
    const bool isSin = (t < 128);          // wave-uniform (waves 0-1 sin, 2-3 cos)
    const int  i0    = (t * 4) & 511;      // freq index of this thread's first dim
    const float c    = -0.018024149455922082f;  // fl32(-ln(10000)/511), matches JAX
    float fr[4];
    #pragma unroll
    for (int k = 0; k < 4; ++k) fr[k] = expf((float)(i0 + k) * c);

    const size_t outRow0 = (size_t)blockIdx.x * 64;
    const floatx4 zero = (floatx4)0.0f;
    #pragma unroll 4
    for (int r = 0; r < 64; ++r) {
        const int p = posBuf[r];
        if (p == PAD_IDX) {                // block-uniform branch: zero row, no trig
            out[(outRow0 + r) * 256 + t] = zero;
            continue;
        }
        const float P = (float)(1025 + p);
        floatx4 v;
        if (isSin) {
            #pragma unroll
            for (int k = 0; k < 4; ++k) v[k] = sinf(P * fr[k]);
        } else {
            #pragma unroll
            for (int k = 0; k < 4; ++k) v[k] = cosf(P * fr[k]);
        }
        out[(outRow0 + r) * 256 + t] = v;
    }
}

extern "C" void kernel_launch(void* const* d_in, const int* in_sizes, int n_in,
                              void* d_out, int out_size, void* d_ws, size_t ws_size,
                              hipStream_t stream) {
    const int* tokens = (const int*)d_in[0];   // [rows, 4096] int32
    float*     out    = (float*)d_out;         // [rows, 4096, 1024] fp32
    // d_in[1] (precomputed table) intentionally unused: recomputed in-register.

    const int seq_len = 4096;
    const int rows    = in_sizes[0] / seq_len; // 32

    fused_kernel<<<rows * 64, 256, 0, stream>>>(tokens, (floatx4*)out, seq_len);
}